// Round 11
// baseline (3837.641 us; speedup 1.0000x reference)
//
#include <hip/hip_runtime.h>
#include <hip/hip_fp16.h>

#define BB 128
#define II 64
#define SS 2048
#define HH 128
#define GG 512   // 4*H
#define OO 64
#define CHS 128          // steps per gx chunk
#define NCH (SS / CHS)   // 16 chunks
#define RING 3           // gx ring depth (chunks)

typedef _Float16 f16x2 __attribute__((ext_vector_type(2)));
union F4H { float4 f4; f16x2 h[4]; };

__device__ __forceinline__ f16x2 pack2(float a, float b) {
    f16x2 r; r.x = (_Float16)a; r.y = (_Float16)b; return r;
}

__device__ __forceinline__ float dot2(f16x2 w, f16x2 v, float c) {
#if __has_builtin(__builtin_amdgcn_fdot2)
    return __builtin_amdgcn_fdot2(w, v, c, false);
#else
    return fmaf((float)w.x, (float)v.x, fmaf((float)w.y, (float)v.y, c));
#endif
}

__device__ __forceinline__ float tanh_f(float v) {
    float a = fabsf(v);
    float e = __expf(-2.0f * a);
    float r = (1.0f - e) * __builtin_amdgcn_rcpf(1.0f + e);
    return v < 0.0f ? -r : r;
}

// generic quad DPP: lane i reads lane (quad_base + perm[i&3]), pattern P packed
template<int P>
__device__ __forceinline__ float qp(float v) {
    return __int_as_float(__builtin_amdgcn_mov_dpp(
        __float_as_int(v), P, 0xF, 0xF, true));
}
template<int C>
__device__ __forceinline__ float qb(float v) { return qp<0x55 * C>(v); }
// DPP row rotate-LEFT by N within 16-lane rows: lane i <- lane (i+N)&15.
template<int N>
__device__ __forceinline__ float rolN(float v) {
    return __int_as_float(__builtin_amdgcn_mov_dpp(
        __float_as_int(v), 0x120 + (16 - N), 0xF, 0xF, true));
}

// LDS-only barrier (no vmcnt drain of in-flight global ops).
__device__ __forceinline__ void barrier_lds() {
    asm volatile("s_waitcnt lgkmcnt(0)\n\ts_barrier" ::: "memory");
}

// device-scope (agent) acquire/release flag ops for producer-consumer
__device__ __forceinline__ unsigned ld_acq(const unsigned* p) {
    return __hip_atomic_load(p, __ATOMIC_ACQUIRE, __HIP_MEMORY_SCOPE_AGENT);
}
__device__ __forceinline__ void st_rel(unsigned* p, unsigned v) {
    __hip_atomic_store(p, v, __ATOMIC_RELEASE, __HIP_MEMORY_SCOPE_AGENT);
}

// ---------------------------------------------------------------------------
// MERGED producer-consumer kernel, one launch, 256 blocks x 512 threads.
//   blocks   0..127: consumer = R10's verified scan body (quad split-K,
//                    2 lgkm-only barriers/step) over ALL 2048 steps, reading
//                    gx from a 3-chunk ring; polls a device-scope flag once
//                    per 128-step chunk.
//   blocks 128..255: producer = gatex for its batch element, chunk by chunk,
//                    into the ring; release-stores flag[chunk]; waits on
//                    consumed[chunk-RING] before slot reuse.
// Rationale: the scan structurally uses only 128 CUs; gatex used to run
// SERIALLY between segments (~280us). Producers now run on the other 128 CUs
// concurrently. Capacity: every block <= 1 CU footprint and 256 blocks <=
// 256 CUs -> all co-resident -> no deadlock. Sync: __syncthreads (vmcnt
// drain) before release-store; acquire-load + __syncthreads on consume
// (thread0's agent-acquire invalidates the CU's L1 / XCD L2).
//
// REGISTER CLIFF (R4/R5/R6): consumer body byte-equivalent to R10's; only
// gx addressing (ring slot, uniform SGPR) and rare boundary code changed.
template<bool PROJ_IN>
__global__ void __launch_bounds__(512)
__attribute__((amdgpu_waves_per_eu(2)))
nlstm_fusedpc(
    const float* __restrict__ x,
    const float* __restrict__ Wx_out, const float* __restrict__ Wh_out,
    const float* __restrict__ b_out,
    const float* __restrict__ Wx_in, const float* __restrict__ Wh_in,
    const float* __restrict__ b_in,
    const float* __restrict__ W_lin, const float* __restrict__ b_lin,
    float* __restrict__ out, f16x2* __restrict__ hws,
    float* __restrict__ gx, unsigned* __restrict__ flag,
    unsigned* __restrict__ consumed)
{
    const int bid = blockIdx.x;
    const int j = threadIdx.x;
    const int u = j >> 2;          // hidden unit (quad index)
    const int g = j & 3;           // gate / k-slice index
    const int jcol = g * HH + u;

    // producer LDS (18.4 KB) + consumer LDS (1.5 KB); both allocated, fine.
    __shared__ __align__(16) f16x2 xs[CHS][36];
    __shared__ __align__(16) f16x2 hb[HH / 2];
    __shared__ __align__(16) f16x2 xib[HH / 2];
    __shared__ __align__(16) f16x2 hib[HH / 2];

    if (bid >= BB) {
        // ================= PRODUCER =================
        const int bp = bid - BB;
        f16x2 wxo[II / 2];
#pragma unroll
        for (int m = 0; m < II / 2; ++m)
            wxo[m] = pack2(Wx_out[(2 * m) * GG + jcol],
                           Wx_out[(2 * m + 1) * GG + jcol]);
        const float bo = b_out[jcol];

        const float* xrow = x + (size_t)bp * II * SS;
        float* gxb = gx + (size_t)bp * (RING * CHS) * GG;
        unsigned* myflag = flag + bp * NCH;
        unsigned* mycons = consumed + bp * NCH;

        int slot = 0;
#pragma unroll 1
        for (int k = 0; k < NCH; ++k) {
            if (k >= RING) {
                if (j == 0)
                    while (ld_acq(&mycons[k - RING]) == 0)
                        __builtin_amdgcn_s_sleep(2);
                __syncthreads();
            }
            const int T0 = k * CHS;
#pragma unroll
            for (int r = 0; r < 8; ++r) {          // stage x tile, coalesced
                const int idx = r * 512 + j;
                const int m = idx >> 7, tt = idx & 127;
                xs[tt][m] = pack2(xrow[(size_t)(2 * m) * SS + T0 + tt],
                                  xrow[(size_t)(2 * m + 1) * SS + T0 + tt]);
            }
            __syncthreads();
#pragma unroll 1
            for (int tt = 0; tt < CHS; ++tt) {
                const float4* xc4 = (const float4*)&xs[tt][0];
                float a0 = bo, a1 = 0.f, a2 = 0.f, a3 = 0.f;
#pragma unroll
                for (int c = 0; c < 8; ++c) {
                    F4H xu; xu.f4 = xc4[c];        // broadcast, conflict-free
                    a0 = dot2(wxo[4 * c + 0], xu.h[0], a0);
                    a1 = dot2(wxo[4 * c + 1], xu.h[1], a1);
                    a2 = dot2(wxo[4 * c + 2], xu.h[2], a2);
                    a3 = dot2(wxo[4 * c + 3], xu.h[3], a3);
                }
                gxb[(size_t)(slot * CHS + tt) * GG + j] = (a0 + a1) + (a2 + a3);
            }
            __syncthreads();   // drains gx stores (vmcnt 0) + xs reuse safety
            if (j == 0) st_rel(&myflag[k], 1u);
            slot = (slot == RING - 1) ? 0 : slot + 1;
        }
        return;
    }

    // ================= CONSUMER (R10 scan body, ring gx) =================
    const int b = bid;

    // split-K register weights: [col c of quad][k-slice of lane g]
    f16x2 who[4][16];
    f16x2 wxi[4][16];
    f16x2 whi[4][16];
#pragma unroll
    for (int c = 0; c < 4; ++c)
#pragma unroll
        for (int c4 = 0; c4 < 4; ++c4)
#pragma unroll
            for (int e = 0; e < 4; ++e) {
                const int k0 = 8 * (g + 4 * c4) + 2 * e;
                const int cc = c * HH + u;
                who[c][4 * c4 + e] = pack2(Wh_out[(size_t)k0 * GG + cc],
                                           Wh_out[(size_t)(k0 + 1) * GG + cc]);
                wxi[c][4 * c4 + e] = pack2(Wx_in[(size_t)k0 * GG + cc],
                                           Wx_in[(size_t)(k0 + 1) * GG + cc]);
                whi[c][4 * c4 + e] = pack2(Wh_in[(size_t)k0 * GG + cc],
                                           Wh_in[(size_t)(k0 + 1) * GG + cc]);
            }

    const float bi2 = b_in[jcol];

    const int   pn = j >> 3;
    const int   ps = j & 7;
    float bl = 0.f;
    F4H wl[2];
    if constexpr (PROJ_IN) {
        bl = b_lin[pn];
#pragma unroll
        for (int q = 0; q < 2; ++q) {
            const int c = 2 * ps + q;
#pragma unroll
            for (int r = 0; r < 4; ++r)
                wl[q].h[r] = pack2(W_lin[pn * HH + 8 * c + 2 * r],
                                   W_lin[pn * HH + 8 * c + 2 * r + 1]);
        }
    }

    float* orow = out + (size_t)b * SS * OO;
    f16x2* hrow = (PROJ_IN ? (f16x2*)nullptr : hws + (size_t)b * SS * (HH / 2));
    const float* gxb = gx + (size_t)b * (RING * CHS) * GG;
    const unsigned* myflag = flag + b * NCH;
    unsigned* mycons = consumed + b * NCH;

    if (j < HH / 2) hb[j] = pack2(0.f, 0.f);
    float c_reg = 0.f, cn_reg = 0.f;
    __syncthreads();

    const float4* hb4 = (const float4*)hb;
    const float4* xi4 = (const float4*)xib;
    const float4* hi4 = (const float4*)hib;
    const bool isT = (g == 3);

    float gx_cur = 0.f;
    int slot = 0;

#pragma unroll 1
    for (int t = 0; t < SS; ++t) {
        const int tl7 = t & (CHS - 1);

        // ---- chunk boundary: release previous slot, acquire next ----
        if (tl7 == 0) {
            const int chunk = t >> 7;
            if (t > 0) {
                __syncthreads();   // all waves' reads of prev slot retired
                if (j == 0) st_rel(&mycons[chunk - 1], 1u);
                slot = (slot == RING - 1) ? 0 : slot + 1;
            }
            if (j == 0)
                while (ld_acq(&myflag[chunk]) == 0)
                    __builtin_amdgcn_s_sleep(2);
            __syncthreads();       // block-wide visibility after acquire
            gx_cur = gxb[(size_t)(slot * CHS) * GG + j];
        }

        // ---- prefetch next gx element (stay within released slot) ----
        float gx_nxt = gx_cur;
        if (tl7 != CHS - 1)
            gx_nxt = gxb[(size_t)(slot * CHS + tl7 + 1) * GG + j];

        // ---- outer gates, split-K: 4 partial dots over this lane's slice ----
        float p0 = 0.f, p1 = 0.f, p2 = 0.f, p3 = 0.f;
#pragma unroll
        for (int c4 = 0; c4 < 4; ++c4) {
            F4H hu; hu.f4 = hb4[g + 4 * c4];
#pragma unroll
            for (int e = 0; e < 4; ++e) {
                p0 = dot2(who[0][4 * c4 + e], hu.h[e], p0);
                p1 = dot2(who[1][4 * c4 + e], hu.h[e], p1);
                p2 = dot2(who[2][4 * c4 + e], hu.h[e], p2);
                p3 = dot2(who[3][4 * c4 + e], hu.h[e], p3);
            }
        }
        p0 += qp<0xB1>(p0); p1 += qp<0xB1>(p1);
        p2 += qp<0xB1>(p2); p3 += qp<0xB1>(p3);
        p0 += qp<0x4E>(p0); p1 += qp<0x4E>(p1);
        p2 += qp<0x4E>(p2); p3 += qp<0x4E>(p3);
        const float totO = (g & 1) ? ((g & 2) ? p3 : p1)
                                   : ((g & 2) ? p2 : p0);
        float acc = totO + gx_cur;

        float ap = isT ? 2.f * acc : acc;
        float s  = __builtin_amdgcn_rcpf(1.f + __expf(-ap));
        float av = isT ? fmaf(2.f, s, -1.f) : s;

        float vi = qb<0>(av), vf = qb<1>(av), vo = qb<2>(av), vg = qb<3>(av);
        float x_in    = vi * vg;
        float h_in    = vf * c_reg;
        float o_outer = vo;

        if constexpr (PROJ_IN) {
            float q0 = 0.f, q1 = 0.f;
            F4H hu0; hu0.f4 = hb4[2 * ps];
            F4H hu1; hu1.f4 = hb4[2 * ps + 1];
            q0 = dot2(wl[0].h[0], hu0.h[0], q0);
            q1 = dot2(wl[0].h[1], hu0.h[1], q1);
            q0 = dot2(wl[0].h[2], hu0.h[2], q0);
            q1 = dot2(wl[0].h[3], hu0.h[3], q1);
            q0 = dot2(wl[1].h[0], hu1.h[0], q0);
            q1 = dot2(wl[1].h[1], hu1.h[1], q1);
            q0 = dot2(wl[1].h[2], hu1.h[2], q0);
            q1 = dot2(wl[1].h[3], hu1.h[3], q1);
            float p = q0 + q1;
            p += rolN<4>(p);
            p += rolN<2>(p);
            p += rolN<1>(p);
            if (ps == 0 && t > 0) orow[(size_t)(t - 1) * OO + pn] = p + bl;
        }

        float xin_n = rolN<4>(x_in);
        float hin_n = rolN<4>(h_in);
        if ((j & 7) == 0) {
            xib[u >> 1] = pack2(x_in, xin_n);
            hib[u >> 1] = pack2(h_in, hin_n);
        }
        barrier_lds();   // B_a

        // ---- inner gates, split-K ----
        float s0 = 0.f, s1 = 0.f, s2 = 0.f, s3 = 0.f;
#pragma unroll
        for (int c4 = 0; c4 < 4; ++c4) {
            F4H xu; xu.f4 = xi4[g + 4 * c4];
#pragma unroll
            for (int e = 0; e < 4; ++e) {
                s0 = dot2(wxi[0][4 * c4 + e], xu.h[e], s0);
                s1 = dot2(wxi[1][4 * c4 + e], xu.h[e], s1);
                s2 = dot2(wxi[2][4 * c4 + e], xu.h[e], s2);
                s3 = dot2(wxi[3][4 * c4 + e], xu.h[e], s3);
            }
        }
#pragma unroll
        for (int c4 = 0; c4 < 4; ++c4) {
            F4H hu2; hu2.f4 = hi4[g + 4 * c4];
#pragma unroll
            for (int e = 0; e < 4; ++e) {
                s0 = dot2(whi[0][4 * c4 + e], hu2.h[e], s0);
                s1 = dot2(whi[1][4 * c4 + e], hu2.h[e], s1);
                s2 = dot2(whi[2][4 * c4 + e], hu2.h[e], s2);
                s3 = dot2(whi[3][4 * c4 + e], hu2.h[e], s3);
            }
        }
        s0 += qp<0xB1>(s0); s1 += qp<0xB1>(s1);
        s2 += qp<0xB1>(s2); s3 += qp<0xB1>(s3);
        s0 += qp<0x4E>(s0); s1 += qp<0x4E>(s1);
        s2 += qp<0x4E>(s2); s3 += qp<0x4E>(s3);
        const float totI = (g & 1) ? ((g & 2) ? s3 : s1)
                                   : ((g & 2) ? s2 : s0);
        float acc2 = totI + bi2;

        float ap2 = isT ? 2.f * acc2 : acc2;
        float s2a = __builtin_amdgcn_rcpf(1.f + __expf(-ap2));
        float av2 = isT ? fmaf(2.f, s2a, -1.f) : s2a;

        float ii = qb<0>(av2), fi = qb<1>(av2), oi = qb<2>(av2), gg = qb<3>(av2);
        float cn_new = fmaf(fi, cn_reg, ii * gg);
        cn_reg = cn_new;
        float c_new = oi * tanh_f(cn_new);
        c_reg = c_new;
        float h_new = o_outer * tanh_f(c_new);

        float hn_n = rolN<4>(h_new);
        if ((j & 7) == 0) {
            f16x2 hp = pack2(h_new, hn_n);
            hb[u >> 1] = hp;
            if constexpr (!PROJ_IN)
                hrow[(size_t)t * (HH / 2) + (j >> 3)] = hp;
        }
        gx_cur = gx_nxt;
        barrier_lds();   // B_b
    }

    if constexpr (PROJ_IN) {
        float q0 = 0.f, q1 = 0.f;
        F4H hu0; hu0.f4 = hb4[2 * ps];
        F4H hu1; hu1.f4 = hb4[2 * ps + 1];
        q0 = dot2(wl[0].h[0], hu0.h[0], q0);
        q1 = dot2(wl[0].h[1], hu0.h[1], q1);
        q0 = dot2(wl[0].h[2], hu0.h[2], q0);
        q1 = dot2(wl[0].h[3], hu0.h[3], q1);
        q0 = dot2(wl[1].h[0], hu1.h[0], q0);
        q1 = dot2(wl[1].h[1], hu1.h[1], q1);
        q0 = dot2(wl[1].h[2], hu1.h[2], q0);
        q1 = dot2(wl[1].h[3], hu1.h[3], q1);
        float p = q0 + q1;
        p += rolN<4>(p);
        p += rolN<2>(p);
        p += rolN<1>(p);
        if (ps == 0) orow[(size_t)(SS - 1) * OO + pn] = p + bl;
    }
}

// ---------------------------------------------------------------------------
// Fully fused fallback (R3/R7-verified): x staged in-scan, in-scan proj.
__global__ void __launch_bounds__(512)
__attribute__((amdgpu_waves_per_eu(2)))
nlstm_fused(
    const float* __restrict__ x,
    const float* __restrict__ Wx_out, const float* __restrict__ Wh_out,
    const float* __restrict__ b_out,
    const float* __restrict__ Wx_in, const float* __restrict__ Wh_in,
    const float* __restrict__ b_in,
    const float* __restrict__ W_lin, const float* __restrict__ b_lin,
    float* __restrict__ out)
{
    const int b = blockIdx.x;
    const int j = threadIdx.x;
    const int u = j >> 2, g = j & 3;
    const int jcol = g * HH + u;

    __shared__ __align__(16) float4 wxf[8 * 512];
    __shared__ __align__(16) f16x2 xt[2][16][36];
    __shared__ __align__(16) f16x2 hb[HH / 2];
    __shared__ __align__(16) f16x2 xib[HH / 2];
    __shared__ __align__(16) f16x2 hib[HH / 2];

    f16x2 who[HH / 2], wxi[HH / 2], whi[HH / 2];
#pragma unroll
    for (int m = 0; m < HH / 2; ++m)
        who[m] = pack2(Wh_out[(2 * m) * GG + jcol], Wh_out[(2 * m + 1) * GG + jcol]);
#pragma unroll
    for (int m = 0; m < HH / 2; ++m)
        wxi[m] = pack2(Wx_in[(2 * m) * GG + jcol], Wx_in[(2 * m + 1) * GG + jcol]);
#pragma unroll
    for (int m = 0; m < HH / 2; ++m)
        whi[m] = pack2(Wh_in[(2 * m) * GG + jcol], Wh_in[(2 * m + 1) * GG + jcol]);

    const float bo = b_out[jcol];
    const float bi2 = b_in[jcol];
    const int pn = j >> 3, ps = j & 7;
    const float bl = b_lin[pn];
    F4H wl[2];
#pragma unroll
    for (int q = 0; q < 2; ++q) {
        const int c = 2 * ps + q;
#pragma unroll
        for (int r = 0; r < 4; ++r)
            wl[q].h[r] = pack2(W_lin[pn * HH + 8 * c + 2 * r],
                               W_lin[pn * HH + 8 * c + 2 * r + 1]);
    }
#pragma unroll
    for (int c = 0; c < 8; ++c) {
        F4H w4;
#pragma unroll
        for (int q = 0; q < 4; ++q)
            w4.h[q] = pack2(Wx_out[(8 * c + 2 * q) * GG + jcol],
                            Wx_out[(8 * c + 2 * q + 1) * GG + jcol]);
        wxf[c * 512 + j] = w4.f4;
    }

    const float* xrow = x + (size_t)b * II * SS;
    float* orow = out + (size_t)b * SS * OO;
    const int xm = j >> 4, xtl = j & 15;
    const float* xg0 = xrow + (size_t)(2 * xm) * SS + xtl;
    const float* xg1 = xrow + (size_t)(2 * xm + 1) * SS + xtl;

    xt[0][xtl][xm] = pack2(xg0[0], xg1[0]);
    if (j < HH / 2) hb[j] = pack2(0.f, 0.f);
    __syncthreads();

    float c_reg = 0.f, cn_reg = 0.f;
    const float4* hb4 = (const float4*)hb;
    const float4* xi4 = (const float4*)xib;
    const float4* hi4 = (const float4*)hib;
    const bool isT = (g == 3);
    float pr0 = 0.f, pr1 = 0.f;

#pragma unroll 1
    for (int t = 0; t < SS; ++t) {
        const int stl = t & 15;
        const int tb = (t >> 4) & 1;
        if (stl == 0) {
            const int Tn = (t + 16 < SS) ? t + 16 : t;
            pr0 = xg0[Tn];
            pr1 = xg1[Tn];
        }
        const float4* xc4 = (const float4*)&xt[tb][stl][0];
        float a0 = bo, a1 = 0.f, a2 = 0.f, a3 = 0.f;
#pragma unroll
        for (int c = 0; c < 8; ++c) {
            F4H xu; xu.f4 = xc4[c];
            F4H wu; wu.f4 = wxf[c * 512 + j];
            a0 = dot2(wu.h[0], xu.h[0], a0);
            a1 = dot2(wu.h[1], xu.h[1], a1);
            a2 = dot2(wu.h[2], xu.h[2], a2);
            a3 = dot2(wu.h[3], xu.h[3], a3);
        }
#pragma unroll
        for (int c = 0; c < 16; ++c) {
            F4H hu; hu.f4 = hb4[c];
            a0 = dot2(who[4 * c + 0], hu.h[0], a0);
            a1 = dot2(who[4 * c + 1], hu.h[1], a1);
            a2 = dot2(who[4 * c + 2], hu.h[2], a2);
            a3 = dot2(who[4 * c + 3], hu.h[3], a3);
        }
        float acc = (a0 + a1) + (a2 + a3);
        float ap = isT ? 2.f * acc : acc;
        float s = __builtin_amdgcn_rcpf(1.f + __expf(-ap));
        float av = isT ? fmaf(2.f, s, -1.f) : s;
        float vi = qb<0>(av), vf = qb<1>(av), vo = qb<2>(av), vg = qb<3>(av);
        float x_in = vi * vg, h_in = vf * c_reg, o_outer = vo;

        float p0 = 0.f, p1 = 0.f;
        {
            F4H hu0; hu0.f4 = hb4[2 * ps];
            F4H hu1; hu1.f4 = hb4[2 * ps + 1];
            p0 = dot2(wl[0].h[0], hu0.h[0], p0);
            p1 = dot2(wl[0].h[1], hu0.h[1], p1);
            p0 = dot2(wl[0].h[2], hu0.h[2], p0);
            p1 = dot2(wl[0].h[3], hu0.h[3], p1);
            p0 = dot2(wl[1].h[0], hu1.h[0], p0);
            p1 = dot2(wl[1].h[1], hu1.h[1], p1);
            p0 = dot2(wl[1].h[2], hu1.h[2], p0);
            p1 = dot2(wl[1].h[3], hu1.h[3], p1);
        }
        float p = p0 + p1;
        p += rolN<4>(p);
        p += rolN<2>(p);
        p += rolN<1>(p);
        if (ps == 0 && t > 0) orow[(size_t)(t - 1) * OO + pn] = p + bl;

        float xin_n = rolN<4>(x_in);
        float hin_n = rolN<4>(h_in);
        if ((j & 7) == 0) {
            xib[u >> 1] = pack2(x_in, xin_n);
            hib[u >> 1] = pack2(h_in, hin_n);
        }
        barrier_lds();

        float b0 = 0.f, b1 = 0.f, b2 = 0.f, b3 = 0.f;
#pragma unroll
        for (int c = 0; c < 16; ++c) {
            F4H xu; xu.f4 = xi4[c];
            b0 = dot2(wxi[4 * c + 0], xu.h[0], b0);
            b1 = dot2(wxi[4 * c + 1], xu.h[1], b1);
            b2 = dot2(wxi[4 * c + 2], xu.h[2], b2);
            b3 = dot2(wxi[4 * c + 3], xu.h[3], b3);
        }
#pragma unroll
        for (int c = 0; c < 16; ++c) {
            F4H hu; hu.f4 = hi4[c];
            b0 = dot2(whi[4 * c + 0], hu.h[0], b0);
            b1 = dot2(whi[4 * c + 1], hu.h[1], b1);
            b2 = dot2(whi[4 * c + 2], hu.h[2], b2);
            b3 = dot2(whi[4 * c + 3], hu.h[3], b3);
        }
        float acc2 = ((b0 + b1) + (b2 + b3)) + bi2;
        float ap2 = isT ? 2.f * acc2 : acc2;
        float s2 = __builtin_amdgcn_rcpf(1.f + __expf(-ap2));
        float av2 = isT ? fmaf(2.f, s2, -1.f) : s2;
        float ii = qb<0>(av2), fi = qb<1>(av2), oi = qb<2>(av2), gg = qb<3>(av2);
        float cn_new = fmaf(fi, cn_reg, ii * gg);
        cn_reg = cn_new;
        float c_new = oi * tanh_f(cn_new);
        c_reg = c_new;
        float h_new = o_outer * tanh_f(c_new);
        float hn_n = rolN<4>(h_new);
        if ((j & 7) == 0) hb[u >> 1] = pack2(h_new, hn_n);
        if (stl == 0) xt[tb ^ 1][xtl][xm] = pack2(pr0, pr1);
        barrier_lds();
    }
    {
        float p0 = 0.f, p1 = 0.f;
        F4H hu0; hu0.f4 = hb4[2 * ps];
        F4H hu1; hu1.f4 = hb4[2 * ps + 1];
        p0 = dot2(wl[0].h[0], hu0.h[0], p0);
        p1 = dot2(wl[0].h[1], hu0.h[1], p1);
        p0 = dot2(wl[0].h[2], hu0.h[2], p0);
        p1 = dot2(wl[0].h[3], hu0.h[3], p1);
        p0 = dot2(wl[1].h[0], hu1.h[0], p0);
        p1 = dot2(wl[1].h[1], hu1.h[1], p1);
        p0 = dot2(wl[1].h[2], hu1.h[2], p0);
        p1 = dot2(wl[1].h[3], hu1.h[3], p1);
        float p = p0 + p1;
        p += rolN<4>(p);
        p += rolN<2>(p);
        p += rolN<1>(p);
        if (ps == 0) orow[(size_t)(SS - 1) * OO + pn] = p + bl;
    }
}

// Post-scan projection: out[r, n] = h[r,:] @ W_lin[n,:] + b_lin[n].
// R11: 1024 blocks (was 512) -> 64 rows/wave, better tail/BW utilization.
__global__ void __launch_bounds__(256)
nlstm_proj(const f16x2* __restrict__ hws, const float* __restrict__ W_lin,
           const float* __restrict__ b_lin, float* __restrict__ out)
{
    const int n  = threadIdx.x & 63;
    const int rg = threadIdx.x >> 6;

    f16x2 wn[HH / 2];
#pragma unroll
    for (int k = 0; k < HH / 2; ++k)
        wn[k] = pack2(W_lin[n * HH + 2 * k], W_lin[n * HH + 2 * k + 1]);
    const float bl = b_lin[n];

    const size_t r0 = (size_t)blockIdx.x * 256 + (size_t)rg * 64;
#pragma unroll 1
    for (int rr = 0; rr < 64; ++rr) {
        const size_t r = r0 + rr;
        const float4* hr = (const float4*)(hws + r * (HH / 2));
        float p0 = 0.f, p1 = 0.f, p2 = 0.f, p3 = 0.f;
#pragma unroll
        for (int c = 0; c < 16; ++c) {
            F4H hu; hu.f4 = hr[c];
            p0 = dot2(wn[4 * c + 0], hu.h[0], p0);
            p1 = dot2(wn[4 * c + 1], hu.h[1], p1);
            p2 = dot2(wn[4 * c + 2], hu.h[2], p2);
            p3 = dot2(wn[4 * c + 3], hu.h[3], p3);
        }
        out[r * OO + n] = ((p0 + p1) + (p2 + p3)) + bl;
    }
}

extern "C" void kernel_launch(void* const* d_in, const int* in_sizes, int n_in,
                              void* d_out, int out_size, void* d_ws, size_t ws_size,
                              hipStream_t stream) {
    (void)in_sizes; (void)n_in; (void)out_size;
    const float* x      = (const float*)d_in[0];
    const float* Wx_out = (const float*)d_in[1];
    const float* Wh_out = (const float*)d_in[2];
    const float* b_out  = (const float*)d_in[3];
    const float* Wx_in  = (const float*)d_in[4];
    const float* Wh_in  = (const float*)d_in[5];
    const float* b_in   = (const float*)d_in[6];
    const float* W_lin  = (const float*)d_in[7];
    const float* b_lin  = (const float*)d_in[8];
    float* out = (float*)d_out;

    const size_t hws_b  = (size_t)BB * SS * (HH / 2) * sizeof(f16x2);      // 64 MiB
    const size_t flg_b  = (size_t)BB * NCH * sizeof(unsigned);             // 8 KB
    const size_t ring_b = (size_t)BB * RING * CHS * GG * sizeof(float);    // 96 MiB
    const size_t need_full = hws_b + 2 * flg_b + ring_b;   // ~167.8 MB
    const size_t need_min  = 2 * flg_b + ring_b;           // ~100.7 MB

    if (d_ws != nullptr && ws_size >= need_full) {
        char* p = (char*)d_ws;
        f16x2* hws = (f16x2*)p;          p += hws_b;
        unsigned* flags = (unsigned*)p;  p += 2 * flg_b;   // flag + consumed
        float* gx = (float*)p;
        unsigned* flag = flags;
        unsigned* consumed = flags + BB * NCH;

        hipMemsetAsync(flags, 0, 2 * flg_b, stream);
        nlstm_fusedpc<false><<<dim3(2 * BB), dim3(512), 0, stream>>>(
            x, Wx_out, Wh_out, b_out, Wx_in, Wh_in, b_in, W_lin, b_lin,
            out, hws, gx, flag, consumed);
        nlstm_proj<<<dim3(1024), dim3(256), 0, stream>>>(hws, W_lin, b_lin, out);
    } else if (d_ws != nullptr && ws_size >= need_min) {
        char* p = (char*)d_ws;
        unsigned* flags = (unsigned*)p;  p += 2 * flg_b;
        float* gx = (float*)p;
        unsigned* flag = flags;
        unsigned* consumed = flags + BB * NCH;

        hipMemsetAsync(flags, 0, 2 * flg_b, stream);
        nlstm_fusedpc<true><<<dim3(2 * BB), dim3(512), 0, stream>>>(
            x, Wx_out, Wh_out, b_out, Wx_in, Wh_in, b_in, W_lin, b_lin,
            out, nullptr, gx, flag, consumed);
    } else {
        nlstm_fused<<<dim3(BB), dim3(512), 0, stream>>>(
            x, Wx_out, Wh_out, b_out, Wx_in, Wh_in, b_in, W_lin, b_lin, out);
    }
}

// Round 12
// 3519.218 us; speedup vs baseline: 1.0905x; 1.0905x over previous
//
#include <hip/hip_runtime.h>
#include <hip/hip_fp16.h>

#define BB 128
#define II 64
#define SS 2048
#define HH 128
#define GG 512   // 4*H
#define OO 64

typedef _Float16 f16x2 __attribute__((ext_vector_type(2)));
union F4H { float4 f4; f16x2 h[4]; };

__device__ __forceinline__ f16x2 pack2(float a, float b) {
    f16x2 r; r.x = (_Float16)a; r.y = (_Float16)b; return r;
}

__device__ __forceinline__ float dot2(f16x2 w, f16x2 v, float c) {
#if __has_builtin(__builtin_amdgcn_fdot2)
    return __builtin_amdgcn_fdot2(w, v, c, false);
#else
    return fmaf((float)w.x, (float)v.x, fmaf((float)w.y, (float)v.y, c));
#endif
}

__device__ __forceinline__ float tanh_f(float v) {
    float a = fabsf(v);
    float e = __expf(-2.0f * a);
    float r = (1.0f - e) * __builtin_amdgcn_rcpf(1.0f + e);
    return v < 0.0f ? -r : r;
}

// generic quad DPP: lane i reads lane (quad_base + perm[i&3]), pattern P packed
template<int P>
__device__ __forceinline__ float qp(float v) {
    return __int_as_float(__builtin_amdgcn_mov_dpp(
        __float_as_int(v), P, 0xF, 0xF, true));
}
template<int C>
__device__ __forceinline__ float qb(float v) { return qp<0x55 * C>(v); }
// DPP row rotate-LEFT by N within 16-lane rows: lane i <- lane (i+N)&15.
template<int N>
__device__ __forceinline__ float rolN(float v) {
    return __int_as_float(__builtin_amdgcn_mov_dpp(
        __float_as_int(v), 0x120 + (16 - N), 0xF, 0xF, true));
}

// LDS-only barrier (no vmcnt drain of in-flight global ops).
__device__ __forceinline__ void barrier_lds() {
    asm volatile("s_waitcnt lgkmcnt(0)\n\ts_barrier" ::: "memory");
}

// ---------------------------------------------------------------------------
// Time-parallel precompute: gx[bb][tl][j] = b_out[jcol] + x[bb,:,T]·Wx_out[:,jcol]
// stored chunk-local, PERMUTED by scan thread index j.
// R12: 2-step ILP (two timesteps per iteration, independent accumulators) —
// producer-side only, large register headroom here, zero cliff risk.
// NOTE (R11 lesson): do NOT run this concurrently with the scan — full-chip
// concurrency slowed the latency-bound scan 15%/step (clock droop / block
// packing), costing more than the ~330us of serial time it hid.
__global__ void __launch_bounds__(512)
nlstm_gatex(const float* __restrict__ x, const float* __restrict__ Wx_out,
            const float* __restrict__ b_out, float* __restrict__ gx,
            int t0, int nchunk)
{
    const int bb  = blockIdx.x / nchunk;
    const int tcw = blockIdx.x % nchunk;
    const int j   = threadIdx.x;
    const int u = j >> 2, g = j & 3;
    const int jcol = g * HH + u;

    __shared__ __align__(16) f16x2 xs[128][36];   // 18.4 KB

    f16x2 wxo[II / 2];
#pragma unroll
    for (int m = 0; m < II / 2; ++m)
        wxo[m] = pack2(Wx_out[(2 * m) * GG + jcol],
                       Wx_out[(2 * m + 1) * GG + jcol]);
    const float bo = b_out[jcol];

    const float* xrow = x + (size_t)bb * II * SS;
    const int T0 = t0 + tcw * 128;
#pragma unroll
    for (int r = 0; r < 8; ++r) {
        const int idx = r * 512 + j;
        const int m = idx >> 7, tt = idx & 127;
        xs[tt][m] = pack2(xrow[(size_t)(2 * m) * SS + T0 + tt],
                          xrow[(size_t)(2 * m + 1) * SS + T0 + tt]);
    }
    __syncthreads();

    const size_t obase = ((size_t)bb * nchunk * 128 + (size_t)tcw * 128) * GG + j;
#pragma unroll 1
    for (int tt = 0; tt < 128; tt += 2) {
        const float4* xa4 = (const float4*)&xs[tt][0];
        const float4* xb4 = (const float4*)&xs[tt + 1][0];
        float a0 = bo, a1 = 0.f, a2 = 0.f, a3 = 0.f;
        float b0 = bo, b1 = 0.f, b2 = 0.f, b3 = 0.f;
#pragma unroll
        for (int c = 0; c < 8; ++c) {
            F4H xu; xu.f4 = xa4[c];
            F4H xv; xv.f4 = xb4[c];
            a0 = dot2(wxo[4 * c + 0], xu.h[0], a0);
            a1 = dot2(wxo[4 * c + 1], xu.h[1], a1);
            a2 = dot2(wxo[4 * c + 2], xu.h[2], a2);
            a3 = dot2(wxo[4 * c + 3], xu.h[3], a3);
            b0 = dot2(wxo[4 * c + 0], xv.h[0], b0);
            b1 = dot2(wxo[4 * c + 1], xv.h[1], b1);
            b2 = dot2(wxo[4 * c + 2], xv.h[2], b2);
            b3 = dot2(wxo[4 * c + 3], xv.h[3], b3);
        }
        gx[obase + (size_t)tt * GG]       = (a0 + a1) + (a2 + a3);
        gx[obase + (size_t)(tt + 1) * GG] = (b0 + b1) + (b2 + b3);
    }
}

// ---------------------------------------------------------------------------
// Segmented scan (R10-proven, 786us/512 steps): QUAD SPLIT-K. Lane g of quad
// u holds ALL 4 of the quad's gate columns x k-slice {chunks g,g+4,g+8,g+12}
// (192 VGPRs), reads ONLY its k-slice (4 b128 outer + 8 inner vs 16+32),
// computes 4 partial dots, quad butterfly all-reduce (0xB1, 0x4E) recovers
// each lane's own-column total. 2 lgkm-only barriers/step.
//
// REGISTER CLIFF (R4/R5/R6): any net-positive live-register change spills
// loop-resident values to L2-scratch (~2x cost). Body is byte-stable.
template<bool PROJ_IN>
__global__ void __launch_bounds__(512)
__attribute__((amdgpu_waves_per_eu(2)))
nlstm_scan_seg(
    const float* __restrict__ Wh_out,
    const float* __restrict__ Wx_in, const float* __restrict__ Wh_in,
    const float* __restrict__ b_in,
    const float* __restrict__ W_lin, const float* __restrict__ b_lin,
    const float* __restrict__ gx, float* __restrict__ out,
    f16x2* __restrict__ hws, f16x2* __restrict__ hst,
    float* __restrict__ cst, float* __restrict__ cnst,
    int t0, int t1, int Tc)
{
    const int b = blockIdx.x;
    const int j = threadIdx.x;
    const int u = j >> 2;          // hidden unit (quad index)
    const int g = j & 3;           // gate AND k-slice index: 0=i 1=f 2=o 3=g
    const int jcol = g * HH + u;   // this lane's own gate column

    __shared__ __align__(16) f16x2 hb[HH / 2];         // h fp16
    __shared__ __align__(16) f16x2 xib[HH / 2];        // x_in fp16
    __shared__ __align__(16) f16x2 hib[HH / 2];        // h_in fp16

    // split-K register weights: [col c of quad][k-slice of lane g]
    f16x2 who[4][16];   // Wh_out  (64 regs)
    f16x2 wxi[4][16];   // Wx_in   (64 regs)
    f16x2 whi[4][16];   // Wh_in   (64 regs)
#pragma unroll
    for (int c = 0; c < 4; ++c)
#pragma unroll
        for (int c4 = 0; c4 < 4; ++c4)
#pragma unroll
            for (int e = 0; e < 4; ++e) {
                const int k0 = 8 * (g + 4 * c4) + 2 * e;
                const int cc = c * HH + u;
                who[c][4 * c4 + e] = pack2(Wh_out[(size_t)k0 * GG + cc],
                                           Wh_out[(size_t)(k0 + 1) * GG + cc]);
                wxi[c][4 * c4 + e] = pack2(Wx_in[(size_t)k0 * GG + cc],
                                           Wx_in[(size_t)(k0 + 1) * GG + cc]);
                whi[c][4 * c4 + e] = pack2(Wh_in[(size_t)k0 * GG + cc],
                                           Wh_in[(size_t)(k0 + 1) * GG + cc]);
            }

    const float bi2 = b_in[jcol];

    // in-scan projection state (PROJ_IN mode)
    const int   pn = j >> 3;
    const int   ps = j & 7;
    float bl = 0.f;
    F4H wl[2];
    if constexpr (PROJ_IN) {
        bl = b_lin[pn];
#pragma unroll
        for (int q = 0; q < 2; ++q) {
            const int c = 2 * ps + q;
#pragma unroll
            for (int r = 0; r < 4; ++r)
                wl[q].h[r] = pack2(W_lin[pn * HH + 8 * c + 2 * r],
                                   W_lin[pn * HH + 8 * c + 2 * r + 1]);
        }
    }

    float* orow = out + (size_t)b * SS * OO;
    f16x2* hrow = (PROJ_IN ? (f16x2*)nullptr : hws + (size_t)b * SS * (HH / 2));
    const float* gxrow = gx + (size_t)b * Tc * GG;

    // ---- state load ----
    float c_reg, cn_reg;
    if (t0 == 0) {
        if (j < HH / 2) hb[j] = pack2(0.f, 0.f);
        c_reg = 0.f; cn_reg = 0.f;
    } else {
        if (j < HH / 2) hb[j] = hst[b * (HH / 2) + j];
        c_reg  = cst[b * HH + u];
        cn_reg = cnst[b * HH + u];
    }
    __syncthreads();

    const float4* hb4 = (const float4*)hb;
    const float4* xi4 = (const float4*)xib;
    const float4* hi4 = (const float4*)hib;
    const bool isT = (g == 3);

    float gx_cur = gxrow[j];

#pragma unroll 1
    for (int t = t0; t < t1; ++t) {
        const int tl = t - t0;

        // ---- prefetch next gx element (coalesced 4B/lane) ----
        const int tln = (tl + 1 < Tc) ? tl + 1 : tl;
        const float gx_nxt = gxrow[(size_t)tln * GG + j];

        // ---- outer gates, split-K: 4 partial dots over this lane's slice ----
        float p0 = 0.f, p1 = 0.f, p2 = 0.f, p3 = 0.f;
#pragma unroll
        for (int c4 = 0; c4 < 4; ++c4) {
            F4H hu; hu.f4 = hb4[g + 4 * c4];   // 4 b128 (was 16)
#pragma unroll
            for (int e = 0; e < 4; ++e) {
                p0 = dot2(who[0][4 * c4 + e], hu.h[e], p0);
                p1 = dot2(who[1][4 * c4 + e], hu.h[e], p1);
                p2 = dot2(who[2][4 * c4 + e], hu.h[e], p2);
                p3 = dot2(who[3][4 * c4 + e], hu.h[e], p3);
            }
        }
        p0 += qp<0xB1>(p0); p1 += qp<0xB1>(p1);
        p2 += qp<0xB1>(p2); p3 += qp<0xB1>(p3);
        p0 += qp<0x4E>(p0); p1 += qp<0x4E>(p1);
        p2 += qp<0x4E>(p2); p3 += qp<0x4E>(p3);
        const float totO = (g & 1) ? ((g & 2) ? p3 : p1)
                                   : ((g & 2) ? p2 : p0);
        float acc = totO + gx_cur;

        // unified activation: g<3 sigmoid, g==3 tanh = 2*sigm(2x)-1
        float ap = isT ? 2.f * acc : acc;
        float s  = __builtin_amdgcn_rcpf(1.f + __expf(-ap));
        float av = isT ? fmaf(2.f, s, -1.f) : s;

        // gate combination inside the quad (no LDS, no barrier)
        float vi = qb<0>(av), vf = qb<1>(av), vo = qb<2>(av), vg = qb<3>(av);
        float x_in    = vi * vg;        // i * g
        float h_in    = vf * c_reg;     // f * c
        float o_outer = vo;             // kept for h_new

        // ---- in-scan projection of h_{t-1} (PROJ_IN mode) ----
        if constexpr (PROJ_IN) {
            float q0 = 0.f, q1 = 0.f;
            F4H hu0; hu0.f4 = hb4[2 * ps];
            F4H hu1; hu1.f4 = hb4[2 * ps + 1];
            q0 = dot2(wl[0].h[0], hu0.h[0], q0);
            q1 = dot2(wl[0].h[1], hu0.h[1], q1);
            q0 = dot2(wl[0].h[2], hu0.h[2], q0);
            q1 = dot2(wl[0].h[3], hu0.h[3], q1);
            q0 = dot2(wl[1].h[0], hu1.h[0], q0);
            q1 = dot2(wl[1].h[1], hu1.h[1], q1);
            q0 = dot2(wl[1].h[2], hu1.h[2], q0);
            q1 = dot2(wl[1].h[3], hu1.h[3], q1);
            float p = q0 + q1;
            p += rolN<4>(p);
            p += rolN<2>(p);
            p += rolN<1>(p);
            if (ps == 0 && t > 0) orow[(size_t)(t - 1) * OO + pn] = p + bl;
        }

        // write x_in/h_in pairs (lane j=8k packs units 2k,2k+1 via DPP rol4)
        float xin_n = rolN<4>(x_in);
        float hin_n = rolN<4>(h_in);
        if ((j & 7) == 0) {
            xib[u >> 1] = pack2(x_in, xin_n);
            hib[u >> 1] = pack2(h_in, hin_n);
        }
        barrier_lds();   // B_a: xib/hib visible; hb readers done before write

        // ---- inner gates, split-K: slice of x_in part + h_in part ----
        float s0 = 0.f, s1 = 0.f, s2 = 0.f, s3 = 0.f;
#pragma unroll
        for (int c4 = 0; c4 < 4; ++c4) {
            F4H xu; xu.f4 = xi4[g + 4 * c4];   // 4 b128 (was 16)
#pragma unroll
            for (int e = 0; e < 4; ++e) {
                s0 = dot2(wxi[0][4 * c4 + e], xu.h[e], s0);
                s1 = dot2(wxi[1][4 * c4 + e], xu.h[e], s1);
                s2 = dot2(wxi[2][4 * c4 + e], xu.h[e], s2);
                s3 = dot2(wxi[3][4 * c4 + e], xu.h[e], s3);
            }
        }
#pragma unroll
        for (int c4 = 0; c4 < 4; ++c4) {
            F4H hu2; hu2.f4 = hi4[g + 4 * c4]; // 4 b128 (was 16)
#pragma unroll
            for (int e = 0; e < 4; ++e) {
                s0 = dot2(whi[0][4 * c4 + e], hu2.h[e], s0);
                s1 = dot2(whi[1][4 * c4 + e], hu2.h[e], s1);
                s2 = dot2(whi[2][4 * c4 + e], hu2.h[e], s2);
                s3 = dot2(whi[3][4 * c4 + e], hu2.h[e], s3);
            }
        }
        s0 += qp<0xB1>(s0); s1 += qp<0xB1>(s1);
        s2 += qp<0xB1>(s2); s3 += qp<0xB1>(s3);
        s0 += qp<0x4E>(s0); s1 += qp<0x4E>(s1);
        s2 += qp<0x4E>(s2); s3 += qp<0x4E>(s3);
        const float totI = (g & 1) ? ((g & 2) ? s3 : s1)
                                   : ((g & 2) ? s2 : s0);
        float acc2 = totI + bi2;

        float ap2 = isT ? 2.f * acc2 : acc2;
        float s2a = __builtin_amdgcn_rcpf(1.f + __expf(-ap2));
        float av2 = isT ? fmaf(2.f, s2a, -1.f) : s2a;

        // state update inside the quad (no LDS, no barrier)
        float ii = qb<0>(av2), fi = qb<1>(av2), oi = qb<2>(av2), gg = qb<3>(av2);
        float cn_new = fmaf(fi, cn_reg, ii * gg);
        cn_reg = cn_new;
        float c_new = oi * tanh_f(cn_new);
        c_reg = c_new;
        float h_new = o_outer * tanh_f(c_new);

        float hn_n = rolN<4>(h_new);
        if ((j & 7) == 0) {
            f16x2 hp = pack2(h_new, hn_n);
            hb[u >> 1] = hp;
            if constexpr (!PROJ_IN)
                hrow[(size_t)t * (HH / 2) + (j >> 3)] = hp;  // h_t -> ws
        }
        gx_cur = gx_nxt;
        barrier_lds();   // B_b: h_t visible
    }

    // ---- state save (hb stable after final B_b) ----
    if (j < HH / 2) hst[b * (HH / 2) + j] = hb[j];
    if (g == 0) { cst[b * HH + u] = c_reg; cnst[b * HH + u] = cn_reg; }

    // ---- final projection: out[S-1] (PROJ_IN mode, last segment only) ----
    if constexpr (PROJ_IN) {
        if (t1 == SS) {
            float q0 = 0.f, q1 = 0.f;
            F4H hu0; hu0.f4 = hb4[2 * ps];
            F4H hu1; hu1.f4 = hb4[2 * ps + 1];
            q0 = dot2(wl[0].h[0], hu0.h[0], q0);
            q1 = dot2(wl[0].h[1], hu0.h[1], q1);
            q0 = dot2(wl[0].h[2], hu0.h[2], q0);
            q1 = dot2(wl[0].h[3], hu0.h[3], q1);
            q0 = dot2(wl[1].h[0], hu1.h[0], q0);
            q1 = dot2(wl[1].h[1], hu1.h[1], q1);
            q0 = dot2(wl[1].h[2], hu1.h[2], q0);
            q1 = dot2(wl[1].h[3], hu1.h[3], q1);
            float p = q0 + q1;
            p += rolN<4>(p);
            p += rolN<2>(p);
            p += rolN<1>(p);
            if (ps == 0) orow[(size_t)(SS - 1) * OO + pn] = p + bl;
        }
    }
}

// ---------------------------------------------------------------------------
// Fully fused fallback (R3/R7-verified): x staged in-scan, in-scan proj.
__global__ void __launch_bounds__(512)
__attribute__((amdgpu_waves_per_eu(2)))
nlstm_fused(
    const float* __restrict__ x,
    const float* __restrict__ Wx_out, const float* __restrict__ Wh_out,
    const float* __restrict__ b_out,
    const float* __restrict__ Wx_in, const float* __restrict__ Wh_in,
    const float* __restrict__ b_in,
    const float* __restrict__ W_lin, const float* __restrict__ b_lin,
    float* __restrict__ out)
{
    const int b = blockIdx.x;
    const int j = threadIdx.x;
    const int u = j >> 2, g = j & 3;
    const int jcol = g * HH + u;

    __shared__ __align__(16) float4 wxf[8 * 512];
    __shared__ __align__(16) f16x2 xt[2][16][36];
    __shared__ __align__(16) f16x2 hb[HH / 2];
    __shared__ __align__(16) f16x2 xib[HH / 2];
    __shared__ __align__(16) f16x2 hib[HH / 2];

    f16x2 who[HH / 2], wxi[HH / 2], whi[HH / 2];
#pragma unroll
    for (int m = 0; m < HH / 2; ++m)
        who[m] = pack2(Wh_out[(2 * m) * GG + jcol], Wh_out[(2 * m + 1) * GG + jcol]);
#pragma unroll
    for (int m = 0; m < HH / 2; ++m)
        wxi[m] = pack2(Wx_in[(2 * m) * GG + jcol], Wx_in[(2 * m + 1) * GG + jcol]);
#pragma unroll
    for (int m = 0; m < HH / 2; ++m)
        whi[m] = pack2(Wh_in[(2 * m) * GG + jcol], Wh_in[(2 * m + 1) * GG + jcol]);

    const float bo = b_out[jcol];
    const float bi2 = b_in[jcol];
    const int pn = j >> 3, ps = j & 7;
    const float bl = b_lin[pn];
    F4H wl[2];
#pragma unroll
    for (int q = 0; q < 2; ++q) {
        const int c = 2 * ps + q;
#pragma unroll
        for (int r = 0; r < 4; ++r)
            wl[q].h[r] = pack2(W_lin[pn * HH + 8 * c + 2 * r],
                               W_lin[pn * HH + 8 * c + 2 * r + 1]);
    }
#pragma unroll
    for (int c = 0; c < 8; ++c) {
        F4H w4;
#pragma unroll
        for (int q = 0; q < 4; ++q)
            w4.h[q] = pack2(Wx_out[(8 * c + 2 * q) * GG + jcol],
                            Wx_out[(8 * c + 2 * q + 1) * GG + jcol]);
        wxf[c * 512 + j] = w4.f4;
    }

    const float* xrow = x + (size_t)b * II * SS;
    float* orow = out + (size_t)b * SS * OO;
    const int xm = j >> 4, xtl = j & 15;
    const float* xg0 = xrow + (size_t)(2 * xm) * SS + xtl;
    const float* xg1 = xrow + (size_t)(2 * xm + 1) * SS + xtl;

    xt[0][xtl][xm] = pack2(xg0[0], xg1[0]);
    if (j < HH / 2) hb[j] = pack2(0.f, 0.f);
    __syncthreads();

    float c_reg = 0.f, cn_reg = 0.f;
    const float4* hb4 = (const float4*)hb;
    const float4* xi4 = (const float4*)xib;
    const float4* hi4 = (const float4*)hib;
    const bool isT = (g == 3);
    float pr0 = 0.f, pr1 = 0.f;

#pragma unroll 1
    for (int t = 0; t < SS; ++t) {
        const int stl = t & 15;
        const int tb = (t >> 4) & 1;
        if (stl == 0) {
            const int Tn = (t + 16 < SS) ? t + 16 : t;
            pr0 = xg0[Tn];
            pr1 = xg1[Tn];
        }
        const float4* xc4 = (const float4*)&xt[tb][stl][0];
        float a0 = bo, a1 = 0.f, a2 = 0.f, a3 = 0.f;
#pragma unroll
        for (int c = 0; c < 8; ++c) {
            F4H xu; xu.f4 = xc4[c];
            F4H wu; wu.f4 = wxf[c * 512 + j];
            a0 = dot2(wu.h[0], xu.h[0], a0);
            a1 = dot2(wu.h[1], xu.h[1], a1);
            a2 = dot2(wu.h[2], xu.h[2], a2);
            a3 = dot2(wu.h[3], xu.h[3], a3);
        }
#pragma unroll
        for (int c = 0; c < 16; ++c) {
            F4H hu; hu.f4 = hb4[c];
            a0 = dot2(who[4 * c + 0], hu.h[0], a0);
            a1 = dot2(who[4 * c + 1], hu.h[1], a1);
            a2 = dot2(who[4 * c + 2], hu.h[2], a2);
            a3 = dot2(who[4 * c + 3], hu.h[3], a3);
        }
        float acc = (a0 + a1) + (a2 + a3);
        float ap = isT ? 2.f * acc : acc;
        float s = __builtin_amdgcn_rcpf(1.f + __expf(-ap));
        float av = isT ? fmaf(2.f, s, -1.f) : s;
        float vi = qb<0>(av), vf = qb<1>(av), vo = qb<2>(av), vg = qb<3>(av);
        float x_in = vi * vg, h_in = vf * c_reg, o_outer = vo;

        float p0 = 0.f, p1 = 0.f;
        {
            F4H hu0; hu0.f4 = hb4[2 * ps];
            F4H hu1; hu1.f4 = hb4[2 * ps + 1];
            p0 = dot2(wl[0].h[0], hu0.h[0], p0);
            p1 = dot2(wl[0].h[1], hu0.h[1], p1);
            p0 = dot2(wl[0].h[2], hu0.h[2], p0);
            p1 = dot2(wl[0].h[3], hu0.h[3], p1);
            p0 = dot2(wl[1].h[0], hu1.h[0], p0);
            p1 = dot2(wl[1].h[1], hu1.h[1], p1);
            p0 = dot2(wl[1].h[2], hu1.h[2], p0);
            p1 = dot2(wl[1].h[3], hu1.h[3], p1);
        }
        float p = p0 + p1;
        p += rolN<4>(p);
        p += rolN<2>(p);
        p += rolN<1>(p);
        if (ps == 0 && t > 0) orow[(size_t)(t - 1) * OO + pn] = p + bl;

        float xin_n = rolN<4>(x_in);
        float hin_n = rolN<4>(h_in);
        if ((j & 7) == 0) {
            xib[u >> 1] = pack2(x_in, xin_n);
            hib[u >> 1] = pack2(h_in, hin_n);
        }
        barrier_lds();

        float b0 = 0.f, b1 = 0.f, b2 = 0.f, b3 = 0.f;
#pragma unroll
        for (int c = 0; c < 16; ++c) {
            F4H xu; xu.f4 = xi4[c];
            b0 = dot2(wxi[4 * c + 0], xu.h[0], b0);
            b1 = dot2(wxi[4 * c + 1], xu.h[1], b1);
            b2 = dot2(wxi[4 * c + 2], xu.h[2], b2);
            b3 = dot2(wxi[4 * c + 3], xu.h[3], b3);
        }
#pragma unroll
        for (int c = 0; c < 16; ++c) {
            F4H hu; hu.f4 = hi4[c];
            b0 = dot2(whi[4 * c + 0], hu.h[0], b0);
            b1 = dot2(whi[4 * c + 1], hu.h[1], b1);
            b2 = dot2(whi[4 * c + 2], hu.h[2], b2);
            b3 = dot2(whi[4 * c + 3], hu.h[3], b3);
        }
        float acc2 = ((b0 + b1) + (b2 + b3)) + bi2;
        float ap2 = isT ? 2.f * acc2 : acc2;
        float s2 = __builtin_amdgcn_rcpf(1.f + __expf(-ap2));
        float av2 = isT ? fmaf(2.f, s2, -1.f) : s2;
        float ii = qb<0>(av2), fi = qb<1>(av2), oi = qb<2>(av2), gg = qb<3>(av2);
        float cn_new = fmaf(fi, cn_reg, ii * gg);
        cn_reg = cn_new;
        float c_new = oi * tanh_f(cn_new);
        c_reg = c_new;
        float h_new = o_outer * tanh_f(c_new);
        float hn_n = rolN<4>(h_new);
        if ((j & 7) == 0) hb[u >> 1] = pack2(h_new, hn_n);
        if (stl == 0) xt[tb ^ 1][xtl][xm] = pack2(pr0, pr1);
        barrier_lds();
    }
    {
        float p0 = 0.f, p1 = 0.f;
        F4H hu0; hu0.f4 = hb4[2 * ps];
        F4H hu1; hu1.f4 = hb4[2 * ps + 1];
        p0 = dot2(wl[0].h[0], hu0.h[0], p0);
        p1 = dot2(wl[0].h[1], hu0.h[1], p1);
        p0 = dot2(wl[0].h[2], hu0.h[2], p0);
        p1 = dot2(wl[0].h[3], hu0.h[3], p1);
        p0 = dot2(wl[1].h[0], hu1.h[0], p0);
        p1 = dot2(wl[1].h[1], hu1.h[1], p1);
        p0 = dot2(wl[1].h[2], hu1.h[2], p0);
        p1 = dot2(wl[1].h[3], hu1.h[3], p1);
        float p = p0 + p1;
        p += rolN<4>(p);
        p += rolN<2>(p);
        p += rolN<1>(p);
        if (ps == 0) orow[(size_t)(SS - 1) * OO + pn] = p + bl;
    }
}

// Post-scan projection: out[r, n] = h[r,:] @ W_lin[n,:] + b_lin[n].
// 1024 blocks x 256 threads: wave = 64 output cols of one row, 64 rows/wave.
__global__ void __launch_bounds__(256)
nlstm_proj(const f16x2* __restrict__ hws, const float* __restrict__ W_lin,
           const float* __restrict__ b_lin, float* __restrict__ out)
{
    const int n  = threadIdx.x & 63;
    const int rg = threadIdx.x >> 6;

    f16x2 wn[HH / 2];
#pragma unroll
    for (int k = 0; k < HH / 2; ++k)
        wn[k] = pack2(W_lin[n * HH + 2 * k], W_lin[n * HH + 2 * k + 1]);
    const float bl = b_lin[n];

    const size_t r0 = (size_t)blockIdx.x * 256 + (size_t)rg * 64;
#pragma unroll 1
    for (int rr = 0; rr < 64; ++rr) {
        const size_t r = r0 + rr;
        const float4* hr = (const float4*)(hws + r * (HH / 2));
        float p0 = 0.f, p1 = 0.f, p2 = 0.f, p3 = 0.f;
#pragma unroll
        for (int c = 0; c < 16; ++c) {
            F4H hu; hu.f4 = hr[c];
            p0 = dot2(wn[4 * c + 0], hu.h[0], p0);
            p1 = dot2(wn[4 * c + 1], hu.h[1], p1);
            p2 = dot2(wn[4 * c + 2], hu.h[2], p2);
            p3 = dot2(wn[4 * c + 3], hu.h[3], p3);
        }
        out[r * OO + n] = ((p0 + p1) + (p2 + p3)) + bl;
    }
}

extern "C" void kernel_launch(void* const* d_in, const int* in_sizes, int n_in,
                              void* d_out, int out_size, void* d_ws, size_t ws_size,
                              hipStream_t stream) {
    (void)in_sizes; (void)n_in; (void)out_size;
    const float* x      = (const float*)d_in[0];
    const float* Wx_out = (const float*)d_in[1];
    const float* Wh_out = (const float*)d_in[2];
    const float* b_out  = (const float*)d_in[3];
    const float* Wx_in  = (const float*)d_in[4];
    const float* Wh_in  = (const float*)d_in[5];
    const float* b_in   = (const float*)d_in[6];
    const float* W_lin  = (const float*)d_in[7];
    const float* b_lin  = (const float*)d_in[8];
    float* out = (float*)d_out;

    const size_t hws_b = (size_t)BB * SS * (HH / 2) * sizeof(f16x2);  // 64 MB
    const size_t hst_b = (size_t)BB * (HH / 2) * sizeof(f16x2);       // 32 KB
    const size_t cst_b = (size_t)BB * HH * sizeof(float);             // 64 KB
    const int tcs[5] = {2048, 1024, 512, 256, 128};

    int Tc = 0;
    bool proj_out = false;
    if (d_ws != nullptr) {
        for (int i = 0; i < 5 && Tc == 0; ++i) {
            const size_t gxb = (size_t)BB * tcs[i] * GG * sizeof(float);
            if (ws_size >= hws_b + hst_b + 2 * cst_b + gxb) { Tc = tcs[i]; proj_out = true; }
        }
        for (int i = 0; i < 5 && Tc == 0; ++i) {
            const size_t gxb = (size_t)BB * tcs[i] * GG * sizeof(float);
            if (ws_size >= hst_b + 2 * cst_b + gxb) Tc = tcs[i];
        }
    }

    if (Tc != 0) {
        char* p = (char*)d_ws;
        f16x2* hws = nullptr;
        if (proj_out) { hws = (f16x2*)p; p += hws_b; }
        f16x2* hst = (f16x2*)p; p += hst_b;
        float* cst  = (float*)p; p += cst_b;
        float* cnst = (float*)p; p += cst_b;
        float* gx   = (float*)p;
        const int nchunk = Tc / 128;

        for (int t0 = 0; t0 < SS; t0 += Tc) {
            nlstm_gatex<<<dim3(BB * nchunk), dim3(512), 0, stream>>>(
                x, Wx_out, b_out, gx, t0, nchunk);
            if (proj_out)
                nlstm_scan_seg<false><<<dim3(BB), dim3(512), 0, stream>>>(
                    Wh_out, Wx_in, Wh_in, b_in, W_lin, b_lin, gx, out,
                    hws, hst, cst, cnst, t0, t0 + Tc, Tc);
            else
                nlstm_scan_seg<true><<<dim3(BB), dim3(512), 0, stream>>>(
                    Wh_out, Wx_in, Wh_in, b_in, W_lin, b_lin, gx, out,
                    nullptr, hst, cst, cnst, t0, t0 + Tc, Tc);
        }
        if (proj_out)
            nlstm_proj<<<dim3(1024), dim3(256), 0, stream>>>(hws, W_lin, b_lin, out);
    } else {
        nlstm_fused<<<dim3(BB), dim3(512), 0, stream>>>(
            x, Wx_out, Wh_out, b_out, Wx_in, Wh_in, b_in, W_lin, b_lin, out);
    }
}

// Round 13
// 3483.551 us; speedup vs baseline: 1.1016x; 1.0102x over previous
//
#include <hip/hip_runtime.h>
#include <hip/hip_fp16.h>

#define BB 128
#define II 64
#define SS 2048
#define HH 128
#define GG 512   // 4*H
#define OO 64

typedef _Float16 f16x2 __attribute__((ext_vector_type(2)));
union F4H { float4 f4; f16x2 h[4]; };

__device__ __forceinline__ f16x2 pack2(float a, float b) {
    f16x2 r; r.x = (_Float16)a; r.y = (_Float16)b; return r;
}

__device__ __forceinline__ float dot2(f16x2 w, f16x2 v, float c) {
#if __has_builtin(__builtin_amdgcn_fdot2)
    return __builtin_amdgcn_fdot2(w, v, c, false);
#else
    return fmaf((float)w.x, (float)v.x, fmaf((float)w.y, (float)v.y, c));
#endif
}

__device__ __forceinline__ float tanh_f(float v) {
    float a = fabsf(v);
    float e = __expf(-2.0f * a);
    float r = (1.0f - e) * __builtin_amdgcn_rcpf(1.0f + e);
    return v < 0.0f ? -r : r;
}

// generic quad DPP: lane i reads lane (quad_base + perm[i&3]), pattern P packed
template<int P>
__device__ __forceinline__ float qp(float v) {
    return __int_as_float(__builtin_amdgcn_mov_dpp(
        __float_as_int(v), P, 0xF, 0xF, true));
}
template<int C>
__device__ __forceinline__ float qb(float v) { return qp<0x55 * C>(v); }
// DPP row rotate-LEFT by N within 16-lane rows: lane i <- lane (i+N)&15.
template<int N>
__device__ __forceinline__ float rolN(float v) {
    return __int_as_float(__builtin_amdgcn_mov_dpp(
        __float_as_int(v), 0x120 + (16 - N), 0xF, 0xF, true));
}

// 4-acc quad all-reduce (R13): lane g gets full-quad sum of acc g. 12 VALU
// (was 8 DPP + 8 add + nested selects = ~19). Verified lane-by-lane:
// r01(l0)=p0{l0,l1}, r01(l1)=p1{l0,l1}, r01(l2)=p0{l2,l3}, r01(l3)=p1{l2,l3};
// round ^2 cross-sums the half-quads, each lane keeps its own column.
__device__ __forceinline__ float quad_reduce4(float p0, float p1,
                                              float p2, float p3, int g) {
    const bool s0 = (g & 1) != 0;    // loop-invariant masks, hoisted
    const bool s1 = (g & 2) != 0;
    float z1 = s0 ? p1 : p0, w1 = s0 ? p0 : p1;
    float r01 = z1 + qp<0xB1>(w1);   // [1,0,3,2]
    float z2 = s0 ? p3 : p2, w2 = s0 ? p2 : p3;
    float r23 = z2 + qp<0xB1>(w2);
    float z = s1 ? r23 : r01, w = s1 ? r01 : r23;
    return z + qp<0x4E>(w);          // [2,3,0,1]
}

// LDS-only barrier (no vmcnt drain of in-flight global ops).
__device__ __forceinline__ void barrier_lds() {
    asm volatile("s_waitcnt lgkmcnt(0)\n\ts_barrier" ::: "memory");
}

// ---------------------------------------------------------------------------
// Time-parallel precompute: gx[bb][tl][col] = b_out[col'] + x·Wx_out[:,col'],
// stored chunk-local, PERMUTED by scan thread index.
// R13: 256 threads/block, 64 timesteps/block, TWO columns per thread
// (jcol0, jcol0+64) -> each xs-row read (8 b128) feeds 2 columns: LDS
// instruction count per column HALVED (gatex was LDS-instr-bound).
// Producer side: large register headroom, zero cliff risk.
// R11 lesson: run serially with the scan, never concurrently.
__global__ void __launch_bounds__(256)
nlstm_gatex(const float* __restrict__ x, const float* __restrict__ Wx_out,
            const float* __restrict__ b_out, float* __restrict__ gx,
            int t0, int nchunk64)   // nchunk64 = Tc/64
{
    const int bb  = blockIdx.x / nchunk64;
    const int tcw = blockIdx.x % nchunk64;
    const int j   = threadIdx.x;          // gx slot j and j+256
    const int u0 = j >> 2, g0 = j & 3;
    const int jcol0 = g0 * HH + u0;       // col for slot j
    const int jcol1 = jcol0 + 64;         // col for slot j+256: ((j+256)&3)*128+((j+256)>>2)

    __shared__ __align__(16) f16x2 xs[64][36];   // 9.2 KB

    f16x2 w0[II / 2], w1[II / 2];         // 64 regs
#pragma unroll
    for (int m = 0; m < II / 2; ++m) {
        w0[m] = pack2(Wx_out[(2 * m) * GG + jcol0], Wx_out[(2 * m + 1) * GG + jcol0]);
        w1[m] = pack2(Wx_out[(2 * m) * GG + jcol1], Wx_out[(2 * m + 1) * GG + jcol1]);
    }
    const float bo0 = b_out[jcol0], bo1 = b_out[jcol1];

    const float* xrow = x + (size_t)bb * II * SS;
    const int T0 = t0 + tcw * 64;
#pragma unroll
    for (int r = 0; r < 8; ++r) {         // stage 64 rows x 32 entries
        const int idx = r * 256 + j;
        const int m = idx >> 6, tt = idx & 63;   // coalesced along tt
        xs[tt][m] = pack2(xrow[(size_t)(2 * m) * SS + T0 + tt],
                          xrow[(size_t)(2 * m + 1) * SS + T0 + tt]);
    }
    __syncthreads();

    const size_t obase =
        ((size_t)bb * (size_t)(nchunk64 * 64) + (size_t)tcw * 64) * GG + j;
#pragma unroll 1
    for (int tt = 0; tt < 64; ++tt) {
        const float4* xc4 = (const float4*)&xs[tt][0];
        float a0 = bo0, a1 = 0.f, a2 = 0.f, a3 = 0.f;
        float c0 = bo1, c1 = 0.f, c2 = 0.f, c3 = 0.f;
#pragma unroll
        for (int c = 0; c < 8; ++c) {
            F4H xu; xu.f4 = xc4[c];       // broadcast read serves BOTH cols
            a0 = dot2(w0[4 * c + 0], xu.h[0], a0);
            a1 = dot2(w0[4 * c + 1], xu.h[1], a1);
            a2 = dot2(w0[4 * c + 2], xu.h[2], a2);
            a3 = dot2(w0[4 * c + 3], xu.h[3], a3);
            c0 = dot2(w1[4 * c + 0], xu.h[0], c0);
            c1 = dot2(w1[4 * c + 1], xu.h[1], c1);
            c2 = dot2(w1[4 * c + 2], xu.h[2], c2);
            c3 = dot2(w1[4 * c + 3], xu.h[3], c3);
        }
        const size_t o = obase + (size_t)tt * GG;
        gx[o]       = (a0 + a1) + (a2 + a3);
        gx[o + 256] = (c0 + c1) + (c2 + c3);
    }
}

// ---------------------------------------------------------------------------
// Segmented scan (R10-proven): QUAD SPLIT-K. Lane g of quad u holds ALL 4 of
// the quad's gate columns x k-slice {chunks g,g+4,g+8,g+12} (192 VGPRs),
// reads ONLY its k-slice (4 b128 outer + 8 inner), computes 4 partial dots,
// quad_reduce4 recovers each lane's own-column total. 2 lgkm barriers/step.
//
// REGISTER CLIFF (R4/R5/R6): any net-positive live-register change spills
// loop-resident values to L2-scratch (~2x cost). R13 delta: quad_reduce4
// (select-then-butterfly, -14 VALU/step, transient temps only).
template<bool PROJ_IN>
__global__ void __launch_bounds__(512)
__attribute__((amdgpu_waves_per_eu(2)))
nlstm_scan_seg(
    const float* __restrict__ Wh_out,
    const float* __restrict__ Wx_in, const float* __restrict__ Wh_in,
    const float* __restrict__ b_in,
    const float* __restrict__ W_lin, const float* __restrict__ b_lin,
    const float* __restrict__ gx, float* __restrict__ out,
    f16x2* __restrict__ hws, f16x2* __restrict__ hst,
    float* __restrict__ cst, float* __restrict__ cnst,
    int t0, int t1, int Tc)
{
    const int b = blockIdx.x;
    const int j = threadIdx.x;
    const int u = j >> 2;          // hidden unit (quad index)
    const int g = j & 3;           // gate AND k-slice index: 0=i 1=f 2=o 3=g
    const int jcol = g * HH + u;   // this lane's own gate column

    __shared__ __align__(16) f16x2 hb[HH / 2];         // h fp16
    __shared__ __align__(16) f16x2 xib[HH / 2];        // x_in fp16
    __shared__ __align__(16) f16x2 hib[HH / 2];        // h_in fp16

    // split-K register weights: [col c of quad][k-slice of lane g]
    f16x2 who[4][16];   // Wh_out  (64 regs)
    f16x2 wxi[4][16];   // Wx_in   (64 regs)
    f16x2 whi[4][16];   // Wh_in   (64 regs)
#pragma unroll
    for (int c = 0; c < 4; ++c)
#pragma unroll
        for (int c4 = 0; c4 < 4; ++c4)
#pragma unroll
            for (int e = 0; e < 4; ++e) {
                const int k0 = 8 * (g + 4 * c4) + 2 * e;
                const int cc = c * HH + u;
                who[c][4 * c4 + e] = pack2(Wh_out[(size_t)k0 * GG + cc],
                                           Wh_out[(size_t)(k0 + 1) * GG + cc]);
                wxi[c][4 * c4 + e] = pack2(Wx_in[(size_t)k0 * GG + cc],
                                           Wx_in[(size_t)(k0 + 1) * GG + cc]);
                whi[c][4 * c4 + e] = pack2(Wh_in[(size_t)k0 * GG + cc],
                                           Wh_in[(size_t)(k0 + 1) * GG + cc]);
            }

    const float bi2 = b_in[jcol];

    // in-scan projection state (PROJ_IN mode)
    const int   pn = j >> 3;
    const int   ps = j & 7;
    float bl = 0.f;
    F4H wl[2];
    if constexpr (PROJ_IN) {
        bl = b_lin[pn];
#pragma unroll
        for (int q = 0; q < 2; ++q) {
            const int c = 2 * ps + q;
#pragma unroll
            for (int r = 0; r < 4; ++r)
                wl[q].h[r] = pack2(W_lin[pn * HH + 8 * c + 2 * r],
                                   W_lin[pn * HH + 8 * c + 2 * r + 1]);
        }
    }

    float* orow = out + (size_t)b * SS * OO;
    f16x2* hrow = (PROJ_IN ? (f16x2*)nullptr : hws + (size_t)b * SS * (HH / 2));
    const float* gxrow = gx + (size_t)b * Tc * GG;

    // ---- state load ----
    float c_reg, cn_reg;
    if (t0 == 0) {
        if (j < HH / 2) hb[j] = pack2(0.f, 0.f);
        c_reg = 0.f; cn_reg = 0.f;
    } else {
        if (j < HH / 2) hb[j] = hst[b * (HH / 2) + j];
        c_reg  = cst[b * HH + u];
        cn_reg = cnst[b * HH + u];
    }
    __syncthreads();

    const float4* hb4 = (const float4*)hb;
    const float4* xi4 = (const float4*)xib;
    const float4* hi4 = (const float4*)hib;
    const bool isT = (g == 3);

    float gx_cur = gxrow[j];

#pragma unroll 1
    for (int t = t0; t < t1; ++t) {
        const int tl = t - t0;

        // ---- prefetch next gx element (coalesced 4B/lane) ----
        const int tln = (tl + 1 < Tc) ? tl + 1 : tl;
        const float gx_nxt = gxrow[(size_t)tln * GG + j];

        // ---- outer gates, split-K: 4 partial dots over this lane's slice ----
        float p0 = 0.f, p1 = 0.f, p2 = 0.f, p3 = 0.f;
#pragma unroll
        for (int c4 = 0; c4 < 4; ++c4) {
            F4H hu; hu.f4 = hb4[g + 4 * c4];   // 4 b128 (was 16)
#pragma unroll
            for (int e = 0; e < 4; ++e) {
                p0 = dot2(who[0][4 * c4 + e], hu.h[e], p0);
                p1 = dot2(who[1][4 * c4 + e], hu.h[e], p1);
                p2 = dot2(who[2][4 * c4 + e], hu.h[e], p2);
                p3 = dot2(who[3][4 * c4 + e], hu.h[e], p3);
            }
        }
        float acc = quad_reduce4(p0, p1, p2, p3, g) + gx_cur;

        // unified activation: g<3 sigmoid, g==3 tanh = 2*sigm(2x)-1
        float ap = isT ? 2.f * acc : acc;
        float s  = __builtin_amdgcn_rcpf(1.f + __expf(-ap));
        float av = isT ? fmaf(2.f, s, -1.f) : s;

        // gate combination inside the quad (no LDS, no barrier)
        float vi = qb<0>(av), vf = qb<1>(av), vo = qb<2>(av), vg = qb<3>(av);
        float x_in    = vi * vg;        // i * g
        float h_in    = vf * c_reg;     // f * c
        float o_outer = vo;             // kept for h_new

        // ---- in-scan projection of h_{t-1} (PROJ_IN mode) ----
        if constexpr (PROJ_IN) {
            float q0 = 0.f, q1 = 0.f;
            F4H hu0; hu0.f4 = hb4[2 * ps];
            F4H hu1; hu1.f4 = hb4[2 * ps + 1];
            q0 = dot2(wl[0].h[0], hu0.h[0], q0);
            q1 = dot2(wl[0].h[1], hu0.h[1], q1);
            q0 = dot2(wl[0].h[2], hu0.h[2], q0);
            q1 = dot2(wl[0].h[3], hu0.h[3], q1);
            q0 = dot2(wl[1].h[0], hu1.h[0], q0);
            q1 = dot2(wl[1].h[1], hu1.h[1], q1);
            q0 = dot2(wl[1].h[2], hu1.h[2], q0);
            q1 = dot2(wl[1].h[3], hu1.h[3], q1);
            float p = q0 + q1;
            p += rolN<4>(p);
            p += rolN<2>(p);
            p += rolN<1>(p);
            if (ps == 0 && t > 0) orow[(size_t)(t - 1) * OO + pn] = p + bl;
        }

        // write x_in/h_in pairs (lane j=8k packs units 2k,2k+1 via DPP rol4)
        float xin_n = rolN<4>(x_in);
        float hin_n = rolN<4>(h_in);
        if ((j & 7) == 0) {
            xib[u >> 1] = pack2(x_in, xin_n);
            hib[u >> 1] = pack2(h_in, hin_n);
        }
        barrier_lds();   // B_a: xib/hib visible; hb readers done before write

        // ---- inner gates, split-K: slice of x_in part + h_in part ----
        float s0 = 0.f, s1 = 0.f, s2 = 0.f, s3 = 0.f;
#pragma unroll
        for (int c4 = 0; c4 < 4; ++c4) {
            F4H xu; xu.f4 = xi4[g + 4 * c4];   // 4 b128 (was 16)
#pragma unroll
            for (int e = 0; e < 4; ++e) {
                s0 = dot2(wxi[0][4 * c4 + e], xu.h[e], s0);
                s1 = dot2(wxi[1][4 * c4 + e], xu.h[e], s1);
                s2 = dot2(wxi[2][4 * c4 + e], xu.h[e], s2);
                s3 = dot2(wxi[3][4 * c4 + e], xu.h[e], s3);
            }
        }
#pragma unroll
        for (int c4 = 0; c4 < 4; ++c4) {
            F4H hu2; hu2.f4 = hi4[g + 4 * c4]; // 4 b128 (was 16)
#pragma unroll
            for (int e = 0; e < 4; ++e) {
                s0 = dot2(whi[0][4 * c4 + e], hu2.h[e], s0);
                s1 = dot2(whi[1][4 * c4 + e], hu2.h[e], s1);
                s2 = dot2(whi[2][4 * c4 + e], hu2.h[e], s2);
                s3 = dot2(whi[3][4 * c4 + e], hu2.h[e], s3);
            }
        }
        float acc2 = quad_reduce4(s0, s1, s2, s3, g) + bi2;

        float ap2 = isT ? 2.f * acc2 : acc2;
        float s2a = __builtin_amdgcn_rcpf(1.f + __expf(-ap2));
        float av2 = isT ? fmaf(2.f, s2a, -1.f) : s2a;

        // state update inside the quad (no LDS, no barrier)
        float ii = qb<0>(av2), fi = qb<1>(av2), oi = qb<2>(av2), gg = qb<3>(av2);
        float cn_new = fmaf(fi, cn_reg, ii * gg);
        cn_reg = cn_new;
        float c_new = oi * tanh_f(cn_new);
        c_reg = c_new;
        float h_new = o_outer * tanh_f(c_new);

        float hn_n = rolN<4>(h_new);
        if ((j & 7) == 0) {
            f16x2 hp = pack2(h_new, hn_n);
            hb[u >> 1] = hp;
            if constexpr (!PROJ_IN)
                hrow[(size_t)t * (HH / 2) + (j >> 3)] = hp;  // h_t -> ws
        }
        gx_cur = gx_nxt;
        barrier_lds();   // B_b: h_t visible
    }

    // ---- state save (hb stable after final B_b) ----
    if (j < HH / 2) hst[b * (HH / 2) + j] = hb[j];
    if (g == 0) { cst[b * HH + u] = c_reg; cnst[b * HH + u] = cn_reg; }

    // ---- final projection: out[S-1] (PROJ_IN mode, last segment only) ----
    if constexpr (PROJ_IN) {
        if (t1 == SS) {
            float q0 = 0.f, q1 = 0.f;
            F4H hu0; hu0.f4 = hb4[2 * ps];
            F4H hu1; hu1.f4 = hb4[2 * ps + 1];
            q0 = dot2(wl[0].h[0], hu0.h[0], q0);
            q1 = dot2(wl[0].h[1], hu0.h[1], q1);
            q0 = dot2(wl[0].h[2], hu0.h[2], q0);
            q1 = dot2(wl[0].h[3], hu0.h[3], q1);
            q0 = dot2(wl[1].h[0], hu1.h[0], q0);
            q1 = dot2(wl[1].h[1], hu1.h[1], q1);
            q0 = dot2(wl[1].h[2], hu1.h[2], q0);
            q1 = dot2(wl[1].h[3], hu1.h[3], q1);
            float p = q0 + q1;
            p += rolN<4>(p);
            p += rolN<2>(p);
            p += rolN<1>(p);
            if (ps == 0) orow[(size_t)(SS - 1) * OO + pn] = p + bl;
        }
    }
}

// ---------------------------------------------------------------------------
// Fully fused fallback (R3/R7-verified): x staged in-scan, in-scan proj.
__global__ void __launch_bounds__(512)
__attribute__((amdgpu_waves_per_eu(2)))
nlstm_fused(
    const float* __restrict__ x,
    const float* __restrict__ Wx_out, const float* __restrict__ Wh_out,
    const float* __restrict__ b_out,
    const float* __restrict__ Wx_in, const float* __restrict__ Wh_in,
    const float* __restrict__ b_in,
    const float* __restrict__ W_lin, const float* __restrict__ b_lin,
    float* __restrict__ out)
{
    const int b = blockIdx.x;
    const int j = threadIdx.x;
    const int u = j >> 2, g = j & 3;
    const int jcol = g * HH + u;

    __shared__ __align__(16) float4 wxf[8 * 512];
    __shared__ __align__(16) f16x2 xt[2][16][36];
    __shared__ __align__(16) f16x2 hb[HH / 2];
    __shared__ __align__(16) f16x2 xib[HH / 2];
    __shared__ __align__(16) f16x2 hib[HH / 2];

    f16x2 who[HH / 2], wxi[HH / 2], whi[HH / 2];
#pragma unroll
    for (int m = 0; m < HH / 2; ++m)
        who[m] = pack2(Wh_out[(2 * m) * GG + jcol], Wh_out[(2 * m + 1) * GG + jcol]);
#pragma unroll
    for (int m = 0; m < HH / 2; ++m)
        wxi[m] = pack2(Wx_in[(2 * m) * GG + jcol], Wx_in[(2 * m + 1) * GG + jcol]);
#pragma unroll
    for (int m = 0; m < HH / 2; ++m)
        whi[m] = pack2(Wh_in[(2 * m) * GG + jcol], Wh_in[(2 * m + 1) * GG + jcol]);

    const float bo = b_out[jcol];
    const float bi2 = b_in[jcol];
    const int pn = j >> 3, ps = j & 7;
    const float bl = b_lin[pn];
    F4H wl[2];
#pragma unroll
    for (int q = 0; q < 2; ++q) {
        const int c = 2 * ps + q;
#pragma unroll
        for (int r = 0; r < 4; ++r)
            wl[q].h[r] = pack2(W_lin[pn * HH + 8 * c + 2 * r],
                               W_lin[pn * HH + 8 * c + 2 * r + 1]);
    }
#pragma unroll
    for (int c = 0; c < 8; ++c) {
        F4H w4;
#pragma unroll
        for (int q = 0; q < 4; ++q)
            w4.h[q] = pack2(Wx_out[(8 * c + 2 * q) * GG + jcol],
                            Wx_out[(8 * c + 2 * q + 1) * GG + jcol]);
        wxf[c * 512 + j] = w4.f4;
    }

    const float* xrow = x + (size_t)b * II * SS;
    float* orow = out + (size_t)b * SS * OO;
    const int xm = j >> 4, xtl = j & 15;
    const float* xg0 = xrow + (size_t)(2 * xm) * SS + xtl;
    const float* xg1 = xrow + (size_t)(2 * xm + 1) * SS + xtl;

    xt[0][xtl][xm] = pack2(xg0[0], xg1[0]);
    if (j < HH / 2) hb[j] = pack2(0.f, 0.f);
    __syncthreads();

    float c_reg = 0.f, cn_reg = 0.f;
    const float4* hb4 = (const float4*)hb;
    const float4* xi4 = (const float4*)xib;
    const float4* hi4 = (const float4*)hib;
    const bool isT = (g == 3);
    float pr0 = 0.f, pr1 = 0.f;

#pragma unroll 1
    for (int t = 0; t < SS; ++t) {
        const int stl = t & 15;
        const int tb = (t >> 4) & 1;
        if (stl == 0) {
            const int Tn = (t + 16 < SS) ? t + 16 : t;
            pr0 = xg0[Tn];
            pr1 = xg1[Tn];
        }
        const float4* xc4 = (const float4*)&xt[tb][stl][0];
        float a0 = bo, a1 = 0.f, a2 = 0.f, a3 = 0.f;
#pragma unroll
        for (int c = 0; c < 8; ++c) {
            F4H xu; xu.f4 = xc4[c];
            F4H wu; wu.f4 = wxf[c * 512 + j];
            a0 = dot2(wu.h[0], xu.h[0], a0);
            a1 = dot2(wu.h[1], xu.h[1], a1);
            a2 = dot2(wu.h[2], xu.h[2], a2);
            a3 = dot2(wu.h[3], xu.h[3], a3);
        }
#pragma unroll
        for (int c = 0; c < 16; ++c) {
            F4H hu; hu.f4 = hb4[c];
            a0 = dot2(who[4 * c + 0], hu.h[0], a0);
            a1 = dot2(who[4 * c + 1], hu.h[1], a1);
            a2 = dot2(who[4 * c + 2], hu.h[2], a2);
            a3 = dot2(who[4 * c + 3], hu.h[3], a3);
        }
        float acc = (a0 + a1) + (a2 + a3);
        float ap = isT ? 2.f * acc : acc;
        float s = __builtin_amdgcn_rcpf(1.f + __expf(-ap));
        float av = isT ? fmaf(2.f, s, -1.f) : s;
        float vi = qb<0>(av), vf = qb<1>(av), vo = qb<2>(av), vg = qb<3>(av);
        float x_in = vi * vg, h_in = vf * c_reg, o_outer = vo;

        float p0 = 0.f, p1 = 0.f;
        {
            F4H hu0; hu0.f4 = hb4[2 * ps];
            F4H hu1; hu1.f4 = hb4[2 * ps + 1];
            p0 = dot2(wl[0].h[0], hu0.h[0], p0);
            p1 = dot2(wl[0].h[1], hu0.h[1], p1);
            p0 = dot2(wl[0].h[2], hu0.h[2], p0);
            p1 = dot2(wl[0].h[3], hu0.h[3], p1);
            p0 = dot2(wl[1].h[0], hu1.h[0], p0);
            p1 = dot2(wl[1].h[1], hu1.h[1], p1);
            p0 = dot2(wl[1].h[2], hu1.h[2], p0);
            p1 = dot2(wl[1].h[3], hu1.h[3], p1);
        }
        float p = p0 + p1;
        p += rolN<4>(p);
        p += rolN<2>(p);
        p += rolN<1>(p);
        if (ps == 0 && t > 0) orow[(size_t)(t - 1) * OO + pn] = p + bl;

        float xin_n = rolN<4>(x_in);
        float hin_n = rolN<4>(h_in);
        if ((j & 7) == 0) {
            xib[u >> 1] = pack2(x_in, xin_n);
            hib[u >> 1] = pack2(h_in, hin_n);
        }
        barrier_lds();

        float b0 = 0.f, b1 = 0.f, b2 = 0.f, b3 = 0.f;
#pragma unroll
        for (int c = 0; c < 16; ++c) {
            F4H xu; xu.f4 = xi4[c];
            b0 = dot2(wxi[4 * c + 0], xu.h[0], b0);
            b1 = dot2(wxi[4 * c + 1], xu.h[1], b1);
            b2 = dot2(wxi[4 * c + 2], xu.h[2], b2);
            b3 = dot2(wxi[4 * c + 3], xu.h[3], b3);
        }
#pragma unroll
        for (int c = 0; c < 16; ++c) {
            F4H hu; hu.f4 = hi4[c];
            b0 = dot2(whi[4 * c + 0], hu.h[0], b0);
            b1 = dot2(whi[4 * c + 1], hu.h[1], b1);
            b2 = dot2(whi[4 * c + 2], hu.h[2], b2);
            b3 = dot2(whi[4 * c + 3], hu.h[3], b3);
        }
        float acc2 = ((b0 + b1) + (b2 + b3)) + bi2;
        float ap2 = isT ? 2.f * acc2 : acc2;
        float s2 = __builtin_amdgcn_rcpf(1.f + __expf(-ap2));
        float av2 = isT ? fmaf(2.f, s2, -1.f) : s2;
        float ii = qb<0>(av2), fi = qb<1>(av2), oi = qb<2>(av2), gg = qb<3>(av2);
        float cn_new = fmaf(fi, cn_reg, ii * gg);
        cn_reg = cn_new;
        float c_new = oi * tanh_f(cn_new);
        c_reg = c_new;
        float h_new = o_outer * tanh_f(c_new);
        float hn_n = rolN<4>(h_new);
        if ((j & 7) == 0) hb[u >> 1] = pack2(h_new, hn_n);
        if (stl == 0) xt[tb ^ 1][xtl][xm] = pack2(pr0, pr1);
        barrier_lds();
    }
    {
        float p0 = 0.f, p1 = 0.f;
        F4H hu0; hu0.f4 = hb4[2 * ps];
        F4H hu1; hu1.f4 = hb4[2 * ps + 1];
        p0 = dot2(wl[0].h[0], hu0.h[0], p0);
        p1 = dot2(wl[0].h[1], hu0.h[1], p1);
        p0 = dot2(wl[0].h[2], hu0.h[2], p0);
        p1 = dot2(wl[0].h[3], hu0.h[3], p1);
        p0 = dot2(wl[1].h[0], hu1.h[0], p0);
        p1 = dot2(wl[1].h[1], hu1.h[1], p1);
        p0 = dot2(wl[1].h[2], hu1.h[2], p0);
        p1 = dot2(wl[1].h[3], hu1.h[3], p1);
        float p = p0 + p1;
        p += rolN<4>(p);
        p += rolN<2>(p);
        p += rolN<1>(p);
        if (ps == 0) orow[(size_t)(SS - 1) * OO + pn] = p + bl;
    }
}

// Post-scan projection: out[r, n] = h[r,:] @ W_lin[n,:] + b_lin[n].
// 1024 blocks x 256 threads: wave = 64 output cols of one row, 64 rows/wave.
__global__ void __launch_bounds__(256)
nlstm_proj(const f16x2* __restrict__ hws, const float* __restrict__ W_lin,
           const float* __restrict__ b_lin, float* __restrict__ out)
{
    const int n  = threadIdx.x & 63;
    const int rg = threadIdx.x >> 6;

    f16x2 wn[HH / 2];
#pragma unroll
    for (int k = 0; k < HH / 2; ++k)
        wn[k] = pack2(W_lin[n * HH + 2 * k], W_lin[n * HH + 2 * k + 1]);
    const float bl = b_lin[n];

    const size_t r0 = (size_t)blockIdx.x * 256 + (size_t)rg * 64;
#pragma unroll 1
    for (int rr = 0; rr < 64; ++rr) {
        const size_t r = r0 + rr;
        const float4* hr = (const float4*)(hws + r * (HH / 2));
        float p0 = 0.f, p1 = 0.f, p2 = 0.f, p3 = 0.f;
#pragma unroll
        for (int c = 0; c < 16; ++c) {
            F4H hu; hu.f4 = hr[c];
            p0 = dot2(wn[4 * c + 0], hu.h[0], p0);
            p1 = dot2(wn[4 * c + 1], hu.h[1], p1);
            p2 = dot2(wn[4 * c + 2], hu.h[2], p2);
            p3 = dot2(wn[4 * c + 3], hu.h[3], p3);
        }
        out[r * OO + n] = ((p0 + p1) + (p2 + p3)) + bl;
    }
}

extern "C" void kernel_launch(void* const* d_in, const int* in_sizes, int n_in,
                              void* d_out, int out_size, void* d_ws, size_t ws_size,
                              hipStream_t stream) {
    (void)in_sizes; (void)n_in; (void)out_size;
    const float* x      = (const float*)d_in[0];
    const float* Wx_out = (const float*)d_in[1];
    const float* Wh_out = (const float*)d_in[2];
    const float* b_out  = (const float*)d_in[3];
    const float* Wx_in  = (const float*)d_in[4];
    const float* Wh_in  = (const float*)d_in[5];
    const float* b_in   = (const float*)d_in[6];
    const float* W_lin  = (const float*)d_in[7];
    const float* b_lin  = (const float*)d_in[8];
    float* out = (float*)d_out;

    const size_t hws_b = (size_t)BB * SS * (HH / 2) * sizeof(f16x2);  // 64 MB
    const size_t hst_b = (size_t)BB * (HH / 2) * sizeof(f16x2);       // 32 KB
    const size_t cst_b = (size_t)BB * HH * sizeof(float);             // 64 KB
    const int tcs[5] = {2048, 1024, 512, 256, 128};

    int Tc = 0;
    bool proj_out = false;
    if (d_ws != nullptr) {
        for (int i = 0; i < 5 && Tc == 0; ++i) {
            const size_t gxb = (size_t)BB * tcs[i] * GG * sizeof(float);
            if (ws_size >= hws_b + hst_b + 2 * cst_b + gxb) { Tc = tcs[i]; proj_out = true; }
        }
        for (int i = 0; i < 5 && Tc == 0; ++i) {
            const size_t gxb = (size_t)BB * tcs[i] * GG * sizeof(float);
            if (ws_size >= hst_b + 2 * cst_b + gxb) Tc = tcs[i];
        }
    }

    if (Tc != 0) {
        char* p = (char*)d_ws;
        f16x2* hws = nullptr;
        if (proj_out) { hws = (f16x2*)p; p += hws_b; }
        f16x2* hst = (f16x2*)p; p += hst_b;
        float* cst  = (float*)p; p += cst_b;
        float* cnst = (float*)p; p += cst_b;
        float* gx   = (float*)p;
        const int nchunk64 = Tc / 64;

        for (int t0 = 0; t0 < SS; t0 += Tc) {
            nlstm_gatex<<<dim3(BB * nchunk64), dim3(256), 0, stream>>>(
                x, Wx_out, b_out, gx, t0, nchunk64);
            if (proj_out)
                nlstm_scan_seg<false><<<dim3(BB), dim3(512), 0, stream>>>(
                    Wh_out, Wx_in, Wh_in, b_in, W_lin, b_lin, gx, out,
                    hws, hst, cst, cnst, t0, t0 + Tc, Tc);
            else
                nlstm_scan_seg<true><<<dim3(BB), dim3(512), 0, stream>>>(
                    Wh_out, Wx_in, Wh_in, b_in, W_lin, b_lin, gx, out,
                    nullptr, hst, cst, cnst, t0, t0 + Tc, Tc);
        }
        if (proj_out)
            nlstm_proj<<<dim3(1024), dim3(256), 0, stream>>>(hws, W_lin, b_lin, out);
    } else {
        nlstm_fused<<<dim3(BB), dim3(512), 0, stream>>>(
            x, Wx_out, Wh_out, b_out, Wx_in, Wh_in, b_in, W_lin, b_lin, out);
    }
}